// Round 4
// baseline (2214.494 us; speedup 1.0000x reference)
//
#include <hip/hip_runtime.h>
#include <hip/hip_fp16.h>

#define HH 4096
#define WW 4096

constexpr float C_LAM = 0.1f;   // ALPHA * LAMDA
constexpr float TAU_F = 0.25f;
constexpr int   NITER = 50;

// ---- single-step kernel geometry (round-3, proven) ----
#define BX 64
#define BY 8
#define VEC 4
#define TILE_W (BX * VEC)       // 256 cols per block

// ---- double-step kernel geometry ----
#define TW  64                  // interior cols per block
#define BYT 32                  // interior rows per block
#define ER  (BYT + 4)           // 36 extended rows
#define EC  (TW + 4)            // 68 extended cols
#define ESZ (ER * EC)           // 2448

union H2x4 { float4 f4; __half2 h2[4]; };
union H2x2 { float2 f2; __half2 h2[2]; };

__device__ __forceinline__ float clip1(float v) {
    return fminf(1.0f, fmaxf(-1.0f, v));
}

// iteration 0 (p=0 -> u=x):  p = clip(tau * grad(x)), packed half2.
// Also emits x_h = fp16(x) for subsequent iterations.
__global__ __launch_bounds__(512) void tv_first(const float* __restrict__ x,
                                                __half2* __restrict__ po,
                                                __half* __restrict__ xh)
{
    const int tx = threadIdx.x, ty = threadIdx.y;
    const int i = blockIdx.y * BY + ty;
    const int j = blockIdx.x * TILE_W + tx * VEC;
    const size_t idx = (size_t)i * WW + j;

    float4 xc4 = *(const float4*)(x + idx);
    float4 xd4 = make_float4(0.f, 0.f, 0.f, 0.f);
    if (i < HH - 1) xd4 = *(const float4*)(x + idx + WW);

    float c[4] = {xc4.x, xc4.y, xc4.z, xc4.w};
    float d[4] = {xd4.x, xd4.y, xd4.z, xd4.w};

    float xr = __shfl_down(c[0], 1, 64);          // next lane's first elem
    if (tx == BX - 1 && j + VEC < WW) xr = x[idx + VEC];

    H2x4 o;
#pragma unroll
    for (int e = 0; e < 4; ++e) {
        float gx = (i < HH - 1) ? (d[e] - c[e]) : 0.f;
        float rn = (e < 3) ? c[e + 1] : xr;
        float gy = (j + e < WW - 1) ? (rn - c[e]) : 0.f;
        o.h2[e] = __floats2half2_rn(clip1(TAU_F * gx), clip1(TAU_F * gy));
    }
    *(float4*)(po + idx) = o.f4;

    H2x2 xs;
    xs.h2[0] = __floats2half2_rn(c[0], c[1]);
    xs.h2[1] = __floats2half2_rn(c[2], c[3]);
    *(float2*)(xh + idx) = xs.f2;
}

// -------- two fused Chambolle steps per pass (temporal blocking) --------
// Extended tile E = (BYT+4)x(TW+4); stages computed uniformly over E, valid
// region shrinks one ring per stage; interior (ring-2) is exact and written.
// LDS: p_prev, p_cur (packed half2) + u (f32, updated in place).
__global__ __launch_bounds__(256) void tv_iter2(const __half* __restrict__ xh,
                                                const __half2* __restrict__ pi,
                                                __half2* __restrict__ po)
{
    __shared__ __half2 sp0[ESZ];
    __shared__ __half2 sp1[ESZ];
    __shared__ float   su[ESZ];

    const int tid = threadIdx.x;
    const int r0 = blockIdx.y * BYT;
    const int c0 = blockIdx.x * TW;

    // A: stage p0 over E (addresses clamped to the image; out-of-image
    // values are only ever consumed in the invalid ring)
    for (int t = tid; t < ESZ; t += 256) {
        int er = t / EC, ec = t - er * EC;
        int gi = r0 - 2 + er, gj = c0 - 2 + ec;
        int gic = min(max(gi, 0), HH - 1);
        int gjc = min(max(gj, 0), WW - 1);
        sp0[t] = pi[(size_t)gic * WW + gjc];
    }
    __syncthreads();

    // B: u1 = x - c*div(p0)
    for (int t = tid; t < ESZ; t += 256) {
        int er = t / EC, ec = t - er * EC;
        int gi = r0 - 2 + er, gj = c0 - 2 + ec;
        int gic = min(max(gi, 0), HH - 1);
        int gjc = min(max(gj, 0), WW - 1);
        float xv = __half2float(xh[(size_t)gic * WW + gjc]);
        int tu = (er > 0) ? t - EC : t;
        int tl = (ec > 0) ? t - 1  : t;
        __half2 pc = sp0[t];
        float dx = (gi > 0) ? (__low2float(sp0[tu])  - __low2float(pc))  : 0.f;
        float dy = (gj > 0) ? (__high2float(sp0[tl]) - __high2float(pc)) : 0.f;
        su[t] = xv - C_LAM * (dx + dy);
    }
    __syncthreads();

    // C: p1 = clip(p0 + tau*grad(u1))
    for (int t = tid; t < ESZ; t += 256) {
        int er = t / EC, ec = t - er * EC;
        int gi = r0 - 2 + er, gj = c0 - 2 + ec;
        int td = (er < ER - 1) ? t + EC : t;
        int tr = (ec < EC - 1) ? t + 1  : t;
        float uc = su[t];
        float gx = (gi < HH - 1) ? (su[td] - uc) : 0.f;
        float gy = (gj < WW - 1) ? (su[tr] - uc) : 0.f;
        __half2 pc = sp0[t];
        sp1[t] = __floats2half2_rn(clip1(__low2float(pc)  + TAU_F * gx),
                                   clip1(__high2float(pc) + TAU_F * gy));
    }
    __syncthreads();

    // D: u2 = u1 - c*div(p1 - p0)   (in place on su; avoids re-reading x)
    for (int t = tid; t < ESZ; t += 256) {
        int er = t / EC, ec = t - er * EC;
        int gi = r0 - 2 + er, gj = c0 - 2 + ec;
        int tu = (er > 0) ? t - EC : t;
        int tl = (ec > 0) ? t - 1  : t;
        __half2 a1 = sp1[t],  a0 = sp0[t];
        __half2 b1 = sp1[tu], b0 = sp0[tu];
        __half2 c1 = sp1[tl], c0_ = sp0[tl];
        float dpx_c = __low2float(a1)  - __low2float(a0);
        float dpx_u = __low2float(b1)  - __low2float(b0);
        float dpy_c = __high2float(a1) - __high2float(a0);
        float dpy_l = __high2float(c1) - __high2float(c0_);
        float dx = (gi > 0) ? (dpx_u - dpx_c) : 0.f;
        float dy = (gj > 0) ? (dpy_l - dpy_c) : 0.f;
        su[t] = su[t] - C_LAM * (dx + dy);
    }
    __syncthreads();

    // E: p2 = clip(p1 + tau*grad(u2)) on the interior; write out
    for (int t = tid; t < BYT * TW; t += 256) {
        int ir = t >> 6, ic = t & (TW - 1);     // TW == 64
        int er = ir + 2, ec = ic + 2;
        int e  = er * EC + ec;
        int gi = r0 + ir, gj = c0 + ic;
        float uc = su[e];
        float gx = (gi < HH - 1) ? (su[e + EC] - uc) : 0.f;
        float gy = (gj < WW - 1) ? (su[e + 1]  - uc) : 0.f;
        __half2 pc = sp1[e];
        po[(size_t)gi * WW + gj] =
            __floats2half2_rn(clip1(__low2float(pc)  + TAU_F * gx),
                              clip1(__high2float(pc) + TAU_F * gy));
    }
}

// single fused iteration (round-3, proven) — used once for the odd step
__global__ __launch_bounds__(512) void tv_iter(const __half* __restrict__ xh,
                                               const __half2* __restrict__ pi,
                                               __half2* __restrict__ po)
{
    __shared__ float su[BY + 1][TILE_W + 8];

    const int tx = threadIdx.x, ty = threadIdx.y;
    const int c0 = blockIdx.x * TILE_W;
    const int r0 = blockIdx.y * BY;
    const int i = r0 + ty;
    const int j = c0 + tx * VEC;
    const size_t idx = (size_t)i * WW + j;

    H2x4 pc, pu;
    pc.f4 = *(const float4*)(pi + idx);
    if (i > 0) pu.f4 = *(const float4*)(pi + idx - WW);
    else       pu.f4 = make_float4(0.f, 0.f, 0.f, 0.f);
    H2x2 xs;
    xs.f2 = *(const float2*)(xh + idx);
    float xv[4] = {__low2float(xs.h2[0]), __high2float(xs.h2[0]),
                   __low2float(xs.h2[1]), __high2float(xs.h2[1])};

    float pxc[4], pyc[4], u[4];
#pragma unroll
    for (int e = 0; e < 4; ++e) {
        pxc[e] = __low2float(pc.h2[e]);
        pyc[e] = __high2float(pc.h2[e]);
    }
    float pyl0 = __shfl_up(pyc[3], 1, 64);        // left lane's last py
    if (tx == 0) pyl0 = (j > 0) ? __high2float(pi[idx - 1]) : 0.f;

#pragma unroll
    for (int e = 0; e < 4; ++e) {
        float dx = (i > 0) ? (__low2float(pu.h2[e]) - pxc[e]) : 0.f;
        float left = (e == 0) ? pyl0 : pyc[e - 1];
        float dy = (j + e > 0) ? (left - pyc[e]) : 0.f;
        u[e] = xv[e] - C_LAM * (dx + dy);
        su[ty][tx * VEC + e] = u[e];
    }

    if (ty == 0) {
        const int ii = r0 + BY;
        float v[4] = {0.f, 0.f, 0.f, 0.f};
        float qy3 = 0.f;
        H2x4 qc, qu;
        H2x2 x2;
        x2.f2 = make_float2(0.f, 0.f);
        const size_t id2 = (size_t)ii * WW + j;
        if (ii < HH) {
            qc.f4 = *(const float4*)(pi + id2);
            qu.f4 = *(const float4*)(pi + id2 - WW);
            x2.f2 = *(const float2*)(xh + id2);
            qy3 = __high2float(qc.h2[3]);
        }
        float ql0 = __shfl_up(qy3, 1, 64);
        if (ii < HH) {
            if (tx == 0) ql0 = (j > 0) ? __high2float(pi[id2 - 1]) : 0.f;
            float x2v[4] = {__low2float(x2.h2[0]), __high2float(x2.h2[0]),
                            __low2float(x2.h2[1]), __high2float(x2.h2[1])};
            float qy[4], qx[4];
#pragma unroll
            for (int e = 0; e < 4; ++e) {
                qx[e] = __low2float(qc.h2[e]);
                qy[e] = __high2float(qc.h2[e]);
            }
#pragma unroll
            for (int e = 0; e < 4; ++e) {
                float dx = __low2float(qu.h2[e]) - qx[e];
                float left = (e == 0) ? ql0 : qy[e - 1];
                float dy = (j + e > 0) ? (left - qy[e]) : 0.f;
                v[e] = x2v[e] - C_LAM * (dx + dy);
            }
        }
#pragma unroll
        for (int e = 0; e < 4; ++e) su[BY][tx * VEC + e] = v[e];
    }

    if (ty == 1 && tx < BY) {
        const int jj = c0 + TILE_W;
        float v = 0.f;
        if (jj < WW) {
            const int i2 = r0 + tx;
            const size_t id2 = (size_t)i2 * WW + jj;
            __half2 qc = pi[id2];
            float qx = __low2float(qc), qy = __high2float(qc);
            float dx = (i2 > 0) ? (__low2float(pi[id2 - WW]) - qx) : 0.f;
            float dy = __high2float(pi[id2 - 1]) - qy;
            v = __half2float(xh[id2]) - C_LAM * (dx + dy);
        }
        su[tx][TILE_W] = v;
    }

    __syncthreads();

    float uu[4];
#pragma unroll
    for (int e = 0; e < 4; ++e) uu[e] = su[ty + 1][tx * VEC + e];
    float ur = su[ty][tx * VEC + VEC];

    H2x4 o;
#pragma unroll
    for (int e = 0; e < 4; ++e) {
        float gx = (i < HH - 1) ? (uu[e] - u[e]) : 0.f;
        float rn = (e < 3) ? u[e + 1] : ur;
        float gy = (j + e < WW - 1) ? (rn - u[e]) : 0.f;
        o.h2[e] = __floats2half2_rn(clip1(pxc[e] + TAU_F * gx),
                                    clip1(pyc[e] + TAU_F * gy));
    }
    *(float4*)(po + idx) = o.f4;
}

// out = x - C*div(p)   (uses the ORIGINAL f32 x for final accuracy)
__global__ __launch_bounds__(512) void tv_out(const float* __restrict__ x,
                                              const __half2* __restrict__ pi,
                                              float* __restrict__ out)
{
    const int tx = threadIdx.x, ty = threadIdx.y;
    const int i = blockIdx.y * BY + ty;
    const int j = blockIdx.x * TILE_W + tx * VEC;
    const size_t idx = (size_t)i * WW + j;

    H2x4 pc, pu;
    pc.f4 = *(const float4*)(pi + idx);
    if (i > 0) pu.f4 = *(const float4*)(pi + idx - WW);
    else       pu.f4 = make_float4(0.f, 0.f, 0.f, 0.f);
    float4 xc4 = *(const float4*)(x + idx);
    float xv[4] = {xc4.x, xc4.y, xc4.z, xc4.w};

    float pxc[4], pyc[4];
#pragma unroll
    for (int e = 0; e < 4; ++e) {
        pxc[e] = __low2float(pc.h2[e]);
        pyc[e] = __high2float(pc.h2[e]);
    }
    float pyl0 = __shfl_up(pyc[3], 1, 64);
    if (tx == 0) pyl0 = (j > 0) ? __high2float(pi[idx - 1]) : 0.f;

    float o[4];
#pragma unroll
    for (int e = 0; e < 4; ++e) {
        float dx = (i > 0) ? (__low2float(pu.h2[e]) - pxc[e]) : 0.f;
        float left = (e == 0) ? pyl0 : pyc[e - 1];
        float dy = (j + e > 0) ? (left - pyc[e]) : 0.f;
        o[e] = xv[e] - C_LAM * (dx + dy);
    }
    *(float4*)(out + idx) = make_float4(o[0], o[1], o[2], o[3]);
}

extern "C" void kernel_launch(void* const* d_in, const int* in_sizes, int n_in,
                              void* d_out, int out_size, void* d_ws, size_t ws_size,
                              hipStream_t stream)
{
    const float* x = (const float*)d_in[0];
    float* out = (float*)d_out;
    const size_t N = (size_t)HH * (size_t)WW;

    // ws layout: pA (64 MiB) | pB (64 MiB) | x_h (32 MiB)
    __half2* pA = (__half2*)d_ws;
    __half2* pB = pA + N;
    __half*  xh = (__half*)(pB + N);

    dim3 b1(BX, BY), g1(WW / TILE_W, HH / BY);
    dim3 b2(256), g2(WW / TW, HH / BYT);

    tv_first<<<g1, b1, 0, stream>>>(x, pA, xh);              // iter 1
    __half2 *pin = pA, *pout = pB;
    for (int p = 0; p < 24; ++p) {                           // iters 2..49
        tv_iter2<<<g2, b2, 0, stream>>>(xh, pin, pout);
        __half2* t = pin; pin = pout; pout = t;
    }
    tv_iter<<<g1, b1, 0, stream>>>(xh, pin, pout);           // iter 50
    {
        __half2* t = pin; pin = pout; pout = t;
    }
    tv_out<<<g1, b1, 0, stream>>>(x, pin, out);
}

// Round 6
// 1105.900 us; speedup vs baseline: 2.0024x; 2.0024x over previous
//
#include <hip/hip_runtime.h>
#include <hip/hip_fp16.h>

#define HH 4096
#define WW 4096

constexpr float C_LAM = 0.1f;   // ALPHA * LAMDA
constexpr float TAU_F = 0.25f;

// ---- single-step kernel geometry (round-3, proven) ----
#define BX 64
#define BY 8
#define VEC 4
#define TILE_W (BX * VEC)       // 256 cols per block

// ---- double-step kernel geometry ----
#define TW2 64                  // interior cols
#define TH2 32                  // interior rows
#define ERR 36                  // extended rows  [r0-2, r0+33]
#define ECC 72                  // extended cols  [c0-4, c0+67] (4-aligned)
#define NCH (ECC / 4)           // 18 chunks per row
#define NSL (ERR * NCH)         // 648 chunk-slots
#define LSZ (ERR * ECC)         // 2592 elements per LDS plane

union H2x4 { float4 f4; __half2 h2[4]; };
union H2x2 { float2 f2; __half2 h2[2]; };
union H2U  { __half2 h; unsigned int u; };

__device__ __forceinline__ float clip1(float v) {
    return fminf(1.0f, fmaxf(-1.0f, v));
}

// packed clamp to [-1,1]: v_pk_max_f16 / v_pk_min_f16 (no __hmax2 in ROCm 7.2)
__device__ __forceinline__ __half2 clamp1h2(__half2 v) {
    H2U a; a.h = v;
    unsigned int lo = 0xBC00BC00u;   // (-1.0h, -1.0h)
    unsigned int hi = 0x3C003C00u;   // (+1.0h, +1.0h)
    unsigned int t, r;
    asm("v_pk_max_f16 %0, %1, %2" : "=v"(t) : "v"(a.u), "v"(lo));
    asm("v_pk_min_f16 %0, %1, %2" : "=v"(r) : "v"(t),   "v"(hi));
    H2U b; b.u = r;
    return b.h;
}

// iteration 0 (p=0 -> u=x):  p = clip(tau * grad(x)); also emits x_h = fp16(x)
__global__ __launch_bounds__(512) void tv_first(const float* __restrict__ x,
                                                __half2* __restrict__ po,
                                                __half* __restrict__ xh)
{
    const int tx = threadIdx.x, ty = threadIdx.y;
    const int i = blockIdx.y * BY + ty;
    const int j = blockIdx.x * TILE_W + tx * VEC;
    const size_t idx = (size_t)i * WW + j;

    float4 xc4 = *(const float4*)(x + idx);
    float4 xd4 = make_float4(0.f, 0.f, 0.f, 0.f);
    if (i < HH - 1) xd4 = *(const float4*)(x + idx + WW);

    float c[4] = {xc4.x, xc4.y, xc4.z, xc4.w};
    float d[4] = {xd4.x, xd4.y, xd4.z, xd4.w};

    float xr = __shfl_down(c[0], 1, 64);
    if (tx == BX - 1 && j + VEC < WW) xr = x[idx + VEC];

    H2x4 o;
#pragma unroll
    for (int e = 0; e < 4; ++e) {
        float gx = (i < HH - 1) ? (d[e] - c[e]) : 0.f;
        float rn = (e < 3) ? c[e + 1] : xr;
        float gy = (j + e < WW - 1) ? (rn - c[e]) : 0.f;
        o.h2[e] = __floats2half2_rn(clip1(TAU_F * gx), clip1(TAU_F * gy));
    }
    *(float4*)(po + idx) = o.f4;

    H2x2 xs;
    xs.h2[0] = __floats2half2_rn(c[0], c[1]);
    xs.h2[1] = __floats2half2_rn(c[2], c[3]);
    *(float2*)(xh + idx) = xs.f2;
}

// -------- two fused Chambolle steps, VALU-lean --------
// All index math hoisted; aligned float4 chunks; row guards via clamped-copy
// halos (vertical diffs auto-zero); per-element col guards only.
__global__ __launch_bounds__(256) void tv_iter2(const __half* __restrict__ xh,
                                                const __half2* __restrict__ pi,
                                                __half2* __restrict__ po)
{
    __shared__ __half2 sp0[LSZ];
    __shared__ __half2 sp1[LSZ];
    __shared__ float   su [LSZ];

    const int tid = threadIdx.x;
    const int r0 = blockIdx.y * TH2;
    const int c0 = blockIdx.x * TW2;

    const __half2 tau2 = __float2half2_rn(TAU_F);

    // ---- per-rep setup (3 chunk-slots per thread) ----
    int lb[3], lup[3], llf[3], ldn[3], lrt[3], gj0a[3], gofs[3];
#pragma unroll
    for (int r = 0; r < 3; ++r) {
        int slot = tid + 256 * r;
        if (slot >= NSL) slot = NSL - 1;            // dup slot: benign (same data)
        int cr = slot / NCH;
        int cc = slot - cr * NCH;
        int gi  = r0 - 2 + cr;
        int gj0 = c0 - 4 + cc * 4;
        int gic = min(max(gi, 0), HH - 1);
        int gjc = min(max(gj0, 0), WW - 4);
        gofs[r] = gic * WW + gjc;                   // fits in int
        int l   = cr * ECC + cc * 4;
        lb[r]  = l;
        lup[r] = (cr > 0) ? l - ECC : l;
        llf[r] = (l > 0) ? l - 1 : 0;
        ldn[r] = (cr < ERR - 1) ? l + ECC : l;
        lrt[r] = min(l + 4, LSZ - 1);
        gj0a[r] = gj0;
    }

    // ---- stage A: load p0 + x chunks ----
    __half2 c2[3][4];
    H2x2    xc[3];
#pragma unroll
    for (int r = 0; r < 3; ++r) {
        H2x4 v; v.f4 = *(const float4*)(pi + gofs[r]);
        xc[r].f2    = *(const float2*)(xh + gofs[r]);
        *(float4*)&sp0[lb[r]] = v.f4;
        c2[r][0] = v.h2[0]; c2[r][1] = v.h2[1];
        c2[r][2] = v.h2[2]; c2[r][3] = v.h2[3];
    }
    __syncthreads();

    // ---- stage B: u1 = x - c*div(p0) ----
    float u1v[3][4];
#pragma unroll
    for (int r = 0; r < 3; ++r) {
        H2x4 up; up.f4 = *(float4*)&sp0[lup[r]];
        __half2 lf = sp0[llf[r]];
        float xs[4] = {__low2float(xc[r].h2[0]), __high2float(xc[r].h2[0]),
                       __low2float(xc[r].h2[1]), __high2float(xc[r].h2[1])};
        float4 w;
        float* wp = &w.x;
#pragma unroll
        for (int e = 0; e < 4; ++e) {
            __half2 cc = c2[r][e];
            __half2 le = (e == 0) ? lf : c2[r][e - 1];
            float dx = __low2float(up.h2[e]) - __low2float(cc);   // rows auto-zero
            float dy = __high2float(le) - __high2float(cc);
            dy = (gj0a[r] + e > 0) ? dy : 0.f;
            float u = xs[e] - C_LAM * (dx + dy);
            u1v[r][e] = u;
            wp[e] = u;
        }
        *(float4*)&su[lb[r]] = w;
    }
    __syncthreads();

    // ---- stage C: p1 = clip(p0 + tau*grad(u1)) ----
    __half2 p1v[3][4];
#pragma unroll
    for (int r = 0; r < 3; ++r) {
        float4 dn4 = *(float4*)&su[ldn[r]];
        float  urr = su[lrt[r]];
        float dn[4] = {dn4.x, dn4.y, dn4.z, dn4.w};
        H2x4 w;
#pragma unroll
        for (int e = 0; e < 4; ++e) {
            float uc = u1v[r][e];
            float gx = dn[e] - uc;                                // rows auto-zero
            float rt = (e == 3) ? urr : u1v[r][e + 1];
            float gy = (gj0a[r] + e < WW - 1) ? (rt - uc) : 0.f;
            __half2 g = __float22half2_rn(make_float2(gx, gy));
            __half2 p1 = clamp1h2(__hfma2(g, tau2, c2[r][e]));
            p1v[r][e] = p1;
            w.h2[e] = p1;
        }
        *(float4*)&sp1[lb[r]] = w.f4;
    }
    __syncthreads();

    // ---- stage D: u2 = u1 - c*div(p1 - p0) ----
#pragma unroll
    for (int r = 0; r < 3; ++r) {
        H2x4 a; a.f4 = *(float4*)&sp1[lup[r]];
        H2x4 b; b.f4 = *(float4*)&sp0[lup[r]];
        __half2 qlf = __hsub2(sp1[llf[r]], sp0[llf[r]]);
        __half2 qprev;
        float4 w;
        float* wp = &w.x;
#pragma unroll
        for (int e = 0; e < 4; ++e) {
            __half2 qc = __hsub2(p1v[r][e], c2[r][e]);
            __half2 qu = __hsub2(a.h2[e], b.h2[e]);
            __half2 ql = (e == 0) ? qlf : qprev;
            float dx = __low2float(qu) - __low2float(qc);          // rows auto-zero
            float dy = __high2float(ql) - __high2float(qc);
            dy = (gj0a[r] + e > 0) ? dy : 0.f;
            float u2 = u1v[r][e] - C_LAM * (dx + dy);
            u1v[r][e] = u2;
            wp[e] = u2;
            qprev = qc;
        }
        *(float4*)&su[lb[r]] = w;
    }
    __syncthreads();

    // ---- stage E: p2 = clip(p1 + tau*grad(u2)) on interior; write out ----
#pragma unroll
    for (int r = 0; r < 2; ++r) {
        int slot = tid + 256 * r;                   // < 512 exactly
        int ir = slot >> 4, icc = slot & 15;
        int er = ir + 2, ec = icc * 4 + 4;
        int l  = er * ECC + ec;
        int gi = r0 + ir, gj = c0 + icc * 4;

        float4 uc4 = *(float4*)&su[l];
        float4 ud4 = *(float4*)&su[l + ECC];
        float  urr = su[l + 4];
        H2x4 pp; pp.f4 = *(float4*)&sp1[l];
        float uc[4] = {uc4.x, uc4.y, uc4.z, uc4.w};
        float ud[4] = {ud4.x, ud4.y, ud4.z, ud4.w};

        H2x4 o;
#pragma unroll
        for (int e = 0; e < 4; ++e) {
            float gx = ud[e] - uc[e];                              // rows auto-zero
            float rt = (e == 3) ? urr : uc[e + 1];
            float gy = (gj + e < WW - 1) ? (rt - uc[e]) : 0.f;
            __half2 g = __float22half2_rn(make_float2(gx, gy));
            o.h2[e] = clamp1h2(__hfma2(g, tau2, pp.h2[e]));
        }
        *(float4*)(po + (size_t)gi * WW + gj) = o.f4;
    }
}

// single fused iteration (round-3, proven) — used once for the odd step
__global__ __launch_bounds__(512) void tv_iter(const __half* __restrict__ xh,
                                               const __half2* __restrict__ pi,
                                               __half2* __restrict__ po)
{
    __shared__ float su[BY + 1][TILE_W + 8];

    const int tx = threadIdx.x, ty = threadIdx.y;
    const int c0 = blockIdx.x * TILE_W;
    const int r0 = blockIdx.y * BY;
    const int i = r0 + ty;
    const int j = c0 + tx * VEC;
    const size_t idx = (size_t)i * WW + j;

    H2x4 pc, pu;
    pc.f4 = *(const float4*)(pi + idx);
    if (i > 0) pu.f4 = *(const float4*)(pi + idx - WW);
    else       pu.f4 = make_float4(0.f, 0.f, 0.f, 0.f);
    H2x2 xs;
    xs.f2 = *(const float2*)(xh + idx);
    float xv[4] = {__low2float(xs.h2[0]), __high2float(xs.h2[0]),
                   __low2float(xs.h2[1]), __high2float(xs.h2[1])};

    float pxc[4], pyc[4], u[4];
#pragma unroll
    for (int e = 0; e < 4; ++e) {
        pxc[e] = __low2float(pc.h2[e]);
        pyc[e] = __high2float(pc.h2[e]);
    }
    float pyl0 = __shfl_up(pyc[3], 1, 64);
    if (tx == 0) pyl0 = (j > 0) ? __high2float(pi[idx - 1]) : 0.f;

#pragma unroll
    for (int e = 0; e < 4; ++e) {
        float dx = (i > 0) ? (__low2float(pu.h2[e]) - pxc[e]) : 0.f;
        float left = (e == 0) ? pyl0 : pyc[e - 1];
        float dy = (j + e > 0) ? (left - pyc[e]) : 0.f;
        u[e] = xv[e] - C_LAM * (dx + dy);
        su[ty][tx * VEC + e] = u[e];
    }

    if (ty == 0) {
        const int ii = r0 + BY;
        float v[4] = {0.f, 0.f, 0.f, 0.f};
        float qy3 = 0.f;
        H2x4 qc, qu;
        H2x2 x2;
        x2.f2 = make_float2(0.f, 0.f);
        const size_t id2 = (size_t)ii * WW + j;
        if (ii < HH) {
            qc.f4 = *(const float4*)(pi + id2);
            qu.f4 = *(const float4*)(pi + id2 - WW);
            x2.f2 = *(const float2*)(xh + id2);
            qy3 = __high2float(qc.h2[3]);
        }
        float ql0 = __shfl_up(qy3, 1, 64);
        if (ii < HH) {
            if (tx == 0) ql0 = (j > 0) ? __high2float(pi[id2 - 1]) : 0.f;
            float x2v[4] = {__low2float(x2.h2[0]), __high2float(x2.h2[0]),
                            __low2float(x2.h2[1]), __high2float(x2.h2[1])};
            float qy[4], qx[4];
#pragma unroll
            for (int e = 0; e < 4; ++e) {
                qx[e] = __low2float(qc.h2[e]);
                qy[e] = __high2float(qc.h2[e]);
            }
#pragma unroll
            for (int e = 0; e < 4; ++e) {
                float dx = __low2float(qu.h2[e]) - qx[e];
                float left = (e == 0) ? ql0 : qy[e - 1];
                float dy = (j + e > 0) ? (left - qy[e]) : 0.f;
                v[e] = x2v[e] - C_LAM * (dx + dy);
            }
        }
#pragma unroll
        for (int e = 0; e < 4; ++e) su[BY][tx * VEC + e] = v[e];
    }

    if (ty == 1 && tx < BY) {
        const int jj = c0 + TILE_W;
        float v = 0.f;
        if (jj < WW) {
            const int i2 = r0 + tx;
            const size_t id2 = (size_t)i2 * WW + jj;
            __half2 qc = pi[id2];
            float qx = __low2float(qc), qy = __high2float(qc);
            float dx = (i2 > 0) ? (__low2float(pi[id2 - WW]) - qx) : 0.f;
            float dy = __high2float(pi[id2 - 1]) - qy;
            v = __half2float(xh[id2]) - C_LAM * (dx + dy);
        }
        su[tx][TILE_W] = v;
    }

    __syncthreads();

    float uu[4];
#pragma unroll
    for (int e = 0; e < 4; ++e) uu[e] = su[ty + 1][tx * VEC + e];
    float ur = su[ty][tx * VEC + VEC];

    H2x4 o;
#pragma unroll
    for (int e = 0; e < 4; ++e) {
        float gx = (i < HH - 1) ? (uu[e] - u[e]) : 0.f;
        float rn = (e < 3) ? u[e + 1] : ur;
        float gy = (j + e < WW - 1) ? (rn - u[e]) : 0.f;
        o.h2[e] = __floats2half2_rn(clip1(pxc[e] + TAU_F * gx),
                                    clip1(pyc[e] + TAU_F * gy));
    }
    *(float4*)(po + idx) = o.f4;
}

// out = x - C*div(p)   (uses the ORIGINAL f32 x for final accuracy)
__global__ __launch_bounds__(512) void tv_out(const float* __restrict__ x,
                                              const __half2* __restrict__ pi,
                                              float* __restrict__ out)
{
    const int tx = threadIdx.x, ty = threadIdx.y;
    const int i = blockIdx.y * BY + ty;
    const int j = blockIdx.x * TILE_W + tx * VEC;
    const size_t idx = (size_t)i * WW + j;

    H2x4 pc, pu;
    pc.f4 = *(const float4*)(pi + idx);
    if (i > 0) pu.f4 = *(const float4*)(pi + idx - WW);
    else       pu.f4 = make_float4(0.f, 0.f, 0.f, 0.f);
    float4 xc4 = *(const float4*)(x + idx);
    float xv[4] = {xc4.x, xc4.y, xc4.z, xc4.w};

    float pxc[4], pyc[4];
#pragma unroll
    for (int e = 0; e < 4; ++e) {
        pxc[e] = __low2float(pc.h2[e]);
        pyc[e] = __high2float(pc.h2[e]);
    }
    float pyl0 = __shfl_up(pyc[3], 1, 64);
    if (tx == 0) pyl0 = (j > 0) ? __high2float(pi[idx - 1]) : 0.f;

    float o[4];
#pragma unroll
    for (int e = 0; e < 4; ++e) {
        float dx = (i > 0) ? (__low2float(pu.h2[e]) - pxc[e]) : 0.f;
        float left = (e == 0) ? pyl0 : pyc[e - 1];
        float dy = (j + e > 0) ? (left - pyc[e]) : 0.f;
        o[e] = xv[e] - C_LAM * (dx + dy);
    }
    *(float4*)(out + idx) = make_float4(o[0], o[1], o[2], o[3]);
}

extern "C" void kernel_launch(void* const* d_in, const int* in_sizes, int n_in,
                              void* d_out, int out_size, void* d_ws, size_t ws_size,
                              hipStream_t stream)
{
    const float* x = (const float*)d_in[0];
    float* out = (float*)d_out;
    const size_t N = (size_t)HH * (size_t)WW;

    // ws layout: pA (64 MiB) | pB (64 MiB) | x_h (32 MiB)
    __half2* pA = (__half2*)d_ws;
    __half2* pB = pA + N;
    __half*  xh = (__half*)(pB + N);

    dim3 b1(BX, BY), g1(WW / TILE_W, HH / BY);
    dim3 b2(256), g2(WW / TW2, HH / TH2);

    tv_first<<<g1, b1, 0, stream>>>(x, pA, xh);              // iter 1
    __half2 *pin = pA, *pout = pB;
    for (int p = 0; p < 24; ++p) {                           // iters 2..49
        tv_iter2<<<g2, b2, 0, stream>>>(xh, pin, pout);
        __half2* t = pin; pin = pout; pout = t;
    }
    tv_iter<<<g1, b1, 0, stream>>>(xh, pin, pout);           // iter 50
    {
        __half2* t = pin; pin = pout; pout = t;
    }
    tv_out<<<g1, b1, 0, stream>>>(x, pin, out);
}